// Round 12
// baseline (679.892 us; speedup 1.0000x reference)
//
#include <hip/hip_runtime.h>
#include <hip/hip_cooperative_groups.h>
#include <hip/hip_bf16.h>
#include <math.h>

namespace cg = cooperative_groups;

// ---------------------------------------------------------------------------
// CrossModalityMultiHeadAttention  (MI355X / gfx950)
// Round 12: ONE cooperative persistent kernel, grid.sync() between phases.
// R10/R11 decomposition showed ~15us fixed cost per graph dispatch x 5
// serialized dispatches ~ 75us of pure overhead; the dependency chain can't
// drop below 5 stages, so the stages become phases of one kernel.
//   P0 prep (conv + ranges + 9 transposes)     1600 units
//   P1 map + qkv-tail GEMM (64x128 tiles)      1024 units
//   P2 qkv-head GEMM                            768 units
//   P3 attention (R7-verified 64-key body)     1024 units
//   P4 out-proj (fp32 into d_out)               512 units
// 36KB smem union -> 4 blocks/CU; __launch_bounds__(256,4).
// ---------------------------------------------------------------------------

typedef __bf16 bf16x8 __attribute__((ext_vector_type(8)));
typedef float  f32x4  __attribute__((ext_vector_type(4)));

#define HID 512
#define NTOK 4096
#define KHEAD 320   // 300 padded

#define AS1(p) ((const __attribute__((address_space(1))) void*)(p))
#define AS3(p) ((__attribute__((address_space(3))) void*)(p))

struct MegaArgs {
    const float* h_head; const float* h_tail;
    const int* bh; const int* bt;
    const float* tsrc[9];
    __bf16*      tdst[9];
    __bf16* hh_bf; __bf16* ht_bf;
    int* ranges;
    // P1: map + qkv-tail
    const __bf16* g1A[4]; const __bf16* g1W[4]; const float* g1b[4]; __bf16* g1C[4]; int g1K[4];
    // P2: qkv-head
    const __bf16* g2A[3]; const __bf16* g2W[3]; const float* g2b[3]; __bf16* g2C[3];
    // P3: attention
    const __bf16* qh; const __bf16* kh; const __bf16* vh;
    const __bf16* qt; const __bf16* kt; const __bf16* vt;
    __bf16* ctxh; __bf16* ctxt;
    // P4: out
    const __bf16* g4A[2]; const __bf16* g4W[2]; const float* g4b[2]; float* g4C[2];
};

// ------------------------------ GEMM 64x128 tile ---------------------------
// R11-verified body, as a device function over a smem arena.
template <typename TC>
__device__ void gemm_unit(const __bf16* __restrict__ A, const __bf16* __restrict__ W,
                          const float* __restrict__ bias, TC* __restrict__ C,
                          int Kp, int bx, int by, char* smem)
{
    __bf16* As = (__bf16*)smem;              // 2 x 2048 elems
    __bf16* Bs = (__bf16*)(smem + 8192);     // 2 x 4096 elems

    const int tid  = threadIdx.x;
    const int wave = tid >> 6;
    const int lane = tid & 63;
    const int quad = lane >> 4;
    const int l16  = lane & 15;
    const int wy   = wave >> 1;
    const int wx   = wave & 1;
    const int rowBase = by * 64;
    const int colBase = bx * 128;

    const int s_row = tid >> 2;
    const int s_kc  = ((tid & 3) ^ ((s_row >> 1) & 3)) * 8;

    const __bf16* gA = A + (size_t)(rowBase + s_row) * Kp + s_kc;
    const __bf16* gB = W + (size_t)(colBase + s_row) * Kp + s_kc;
    const int waveOff = wave * 512;

    f32x4 acc[2][4] = {};
    const int nk = Kp >> 5;

    __syncthreads();   // prior unit/phase LDS reads done before overwrite
    __builtin_amdgcn_global_load_lds(AS1(gA),                   AS3(&As[waveOff]),        16, 0, 0);
    __builtin_amdgcn_global_load_lds(AS1(gB),                   AS3(&Bs[waveOff]),        16, 0, 0);
    __builtin_amdgcn_global_load_lds(AS1(gB + (size_t)64 * Kp), AS3(&Bs[2048 + waveOff]), 16, 0, 0);

    for (int i = 0; i < nk; ++i) {
        const int cur = i & 1;
        __syncthreads();   // drains tile i's loads; prev buf reads done

        if (i + 1 < nk) {
            const int kt = (i + 1) * 32;
            const int nx = cur ^ 1;
            __builtin_amdgcn_global_load_lds(AS1(gA + kt),                   AS3(&As[nx * 2048 + waveOff]),        16, 0, 0);
            __builtin_amdgcn_global_load_lds(AS1(gB + kt),                   AS3(&Bs[nx * 4096 + waveOff]),        16, 0, 0);
            __builtin_amdgcn_global_load_lds(AS1(gB + kt + (size_t)64 * Kp), AS3(&Bs[nx * 4096 + 2048 + waveOff]), 16, 0, 0);
        }

        bf16x8 ar[2], br[4];
        #pragma unroll
        for (int ii = 0; ii < 2; ++ii) {
            const int ra = wy * 32 + ii * 16 + l16;
            ar[ii] = *(const bf16x8*)&As[cur * 2048 + ra * 32 + ((quad ^ ((ra >> 1) & 3)) << 3)];
        }
        #pragma unroll
        for (int jj = 0; jj < 4; ++jj) {
            const int rb = wx * 64 + jj * 16 + l16;
            br[jj] = *(const bf16x8*)&Bs[cur * 4096 + rb * 32 + ((quad ^ ((rb >> 1) & 3)) << 3)];
        }
        #pragma unroll
        for (int ii = 0; ii < 2; ++ii)
            #pragma unroll
            for (int jj = 0; jj < 4; ++jj)
                acc[ii][jj] = __builtin_amdgcn_mfma_f32_16x16x32_bf16(ar[ii], br[jj], acc[ii][jj], 0, 0, 0);
    }

    #pragma unroll
    for (int jj = 0; jj < 4; ++jj) {
        int col = colBase + wx * 64 + jj * 16 + l16;
        float bv = bias[col];
        #pragma unroll
        for (int ii = 0; ii < 2; ++ii) {
            #pragma unroll
            for (int r = 0; r < 4; ++r) {
                int row = rowBase + wy * 32 + ii * 16 + quad * 4 + r;
                C[(size_t)row * HID + col] = (TC)(acc[ii][jj][r] + bv);
            }
        }
    }
}

// ------------------------------ attention unit -----------------------------
// R7-verified 64-key body (no early returns — cooperative phases).
__device__ void attn_unit(const MegaArgs& a, int side, int h, int b, char* smem)
{
    __bf16 (*Qs)[72] = (__bf16(*)[72])(smem);
    __bf16 (*Ks)[72] = (__bf16(*)[72])(smem + 9216);
    __bf16 (*Vt)[72] = (__bf16(*)[72])(smem + 18432);
    __bf16 (*Ps)[72] = (__bf16(*)[72])(smem + 27648);

    const __bf16* Q    = side ? a.qt : a.qh;
    const __bf16* Kg   = side ? a.kh : a.kt;
    const __bf16* Vres = side ? a.vt : a.vh;
    const __bf16* Vctx = side ? a.vh : a.vt;
    __bf16* Out        = side ? a.ctxt : a.ctxh;
    const int* qstart  = side ? a.ranges + 128 : a.ranges;
    const int* qend    = side ? a.ranges + 192 : a.ranges + 64;
    const int* kstart  = side ? a.ranges       : a.ranges + 128;
    const int* kend    = side ? a.ranges + 64  : a.ranges + 192;

    const int qs = qstart[b], qe = qend[b];
    const int ts = kstart[b], te = kend[b];
    const int nq = qe - qs, nk = te - ts;
    if (nq <= 0) return;   // block-uniform, no barriers skipped below

    const int tid  = threadIdx.x;
    const int wave = tid >> 6;
    const int lane = tid & 63;
    const int quad = lane >> 4;
    const int l16  = lane & 15;
    const int srow = tid >> 2;
    const int scol = (tid & 3) * 16;

    if (nk <= 0) {
        __syncthreads();   // prior unit's LDS reads done
        float* meanv = (float*)Qs;
        if (tid < 64) {
            float s = 0.f;
            for (int m = 0; m < NTOK; ++m)
                s += (float)Vctx[(size_t)m * HID + h * 64 + tid];
            meanv[tid] = s / (float)NTOK;
        }
        __syncthreads();
        int d = tid & 63;
        for (int r = qs + (tid >> 6); r < qe; r += 4) {
            size_t off = (size_t)r * HID + h * 64 + d;
            Out[off] = (__bf16)((float)Vres[off] + meanv[d]);
        }
        __syncthreads();   // meanv reads done before next unit overwrites
        return;
    }

    for (int qc = 0; qc < nq; qc += 64) {
        __syncthreads();
        {
            int qg = min(qs + qc + srow, NTOK - 1);
            const __bf16* src = Q + (size_t)qg * HID + h * 64 + scol;
            *(bf16x8*)&Qs[srow][scol]     = *(const bf16x8*)src;
            *(bf16x8*)&Qs[srow][scol + 8] = *(const bf16x8*)(src + 8);
        }
        __syncthreads();
        bf16x8 aq0 = *(const bf16x8*)&Qs[wave * 16 + l16][quad * 8];
        bf16x8 aq1 = *(const bf16x8*)&Qs[wave * 16 + l16][32 + quad * 8];

        f32x4 O[4] = {};
        float Mx[4], L[4];
        #pragma unroll
        for (int r = 0; r < 4; ++r) { Mx[r] = -__builtin_inff(); L[r] = 0.f; }

        for (int kc = 0; kc < nk; kc += 64) {
            __syncthreads();
            {
                int kg = min(ts + kc + srow, NTOK - 1);
                const __bf16* ksrc = Kg + (size_t)kg * HID + h * 64 + scol;
                *(bf16x8*)&Ks[srow][scol]     = *(const bf16x8*)ksrc;
                *(bf16x8*)&Ks[srow][scol + 8] = *(const bf16x8*)(ksrc + 8);
                const __bf16* vsrc = Vctx + (size_t)kg * HID + h * 64 + scol;
                bf16x8 v0 = *(const bf16x8*)vsrc;
                bf16x8 v1 = *(const bf16x8*)(vsrc + 8);
                #pragma unroll
                for (int j = 0; j < 8; ++j) {
                    Vt[scol + j][srow]     = v0[j];
                    Vt[scol + 8 + j][srow] = v1[j];
                }
            }
            __syncthreads();

            f32x4 S[4] = {};
            #pragma unroll
            for (int c = 0; c < 4; ++c) {
                bf16x8 bk0 = *(const bf16x8*)&Ks[c * 16 + l16][quad * 8];
                bf16x8 bk1 = *(const bf16x8*)&Ks[c * 16 + l16][32 + quad * 8];
                S[c] = __builtin_amdgcn_mfma_f32_16x16x32_bf16(aq0, bk0, S[c], 0, 0, 0);
                S[c] = __builtin_amdgcn_mfma_f32_16x16x32_bf16(aq1, bk1, S[c], 0, 0, 0);
            }

            #pragma unroll
            for (int c = 0; c < 4; ++c) {
                bool valid = (ts + kc + c * 16 + l16) < te;
                #pragma unroll
                for (int r = 0; r < 4; ++r)
                    S[c][r] = valid ? S[c][r] * 0.125f : -__builtin_inff();
            }

            float cm[4], ps[4], alpha[4];
            #pragma unroll
            for (int r = 0; r < 4; ++r) {
                float v = fmaxf(fmaxf(S[0][r], S[1][r]), fmaxf(S[2][r], S[3][r]));
                v = fmaxf(v, __shfl_xor(v, 1, 64));
                v = fmaxf(v, __shfl_xor(v, 2, 64));
                v = fmaxf(v, __shfl_xor(v, 4, 64));
                v = fmaxf(v, __shfl_xor(v, 8, 64));
                cm[r] = v;
            }
            #pragma unroll
            for (int r = 0; r < 4; ++r) {
                float nM = fmaxf(Mx[r], cm[r]);
                alpha[r] = __expf(Mx[r] - nM);   // first chunk: exp(-inf)=0
                Mx[r] = nM;
                ps[r] = 0.f;
            }
            #pragma unroll
            for (int c = 0; c < 4; ++c)
                #pragma unroll
                for (int r = 0; r < 4; ++r) {
                    float p = __expf(S[c][r] - Mx[r]);
                    S[c][r] = p;
                    ps[r] += p;
                }
            #pragma unroll
            for (int r = 0; r < 4; ++r) {
                float v = ps[r];
                v += __shfl_xor(v, 1, 64);
                v += __shfl_xor(v, 2, 64);
                v += __shfl_xor(v, 4, 64);
                v += __shfl_xor(v, 8, 64);
                L[r] = L[r] * alpha[r] + v;
            }
            #pragma unroll
            for (int c = 0; c < 4; ++c)
                #pragma unroll
                for (int r = 0; r < 4; ++r)
                    O[c][r] *= alpha[r];

            #pragma unroll
            for (int c = 0; c < 4; ++c)
                #pragma unroll
                for (int r = 0; r < 4; ++r)
                    Ps[wave * 16 + quad * 4 + r][c * 16 + l16] = (__bf16)S[c][r];
            __syncthreads();

            bf16x8 ap0 = *(const bf16x8*)&Ps[wave * 16 + l16][quad * 8];
            bf16x8 ap1 = *(const bf16x8*)&Ps[wave * 16 + l16][32 + quad * 8];
            #pragma unroll
            for (int c = 0; c < 4; ++c) {
                bf16x8 bv0 = *(const bf16x8*)&Vt[c * 16 + l16][quad * 8];
                bf16x8 bv1 = *(const bf16x8*)&Vt[c * 16 + l16][32 + quad * 8];
                O[c] = __builtin_amdgcn_mfma_f32_16x16x32_bf16(ap0, bv0, O[c], 0, 0, 0);
                O[c] = __builtin_amdgcn_mfma_f32_16x16x32_bf16(ap1, bv1, O[c], 0, 0, 0);
            }
        }

        #pragma unroll
        for (int c = 0; c < 4; ++c) {
            int d = h * 64 + c * 16 + l16;
            #pragma unroll
            for (int r = 0; r < 4; ++r) {
                int qrow = qs + qc + wave * 16 + quad * 4 + r;
                if (qrow < qe) {
                    size_t off = (size_t)qrow * HID + d;
                    Out[off] = (__bf16)((float)Vres[off] + O[c][r] / L[r]);
                }
            }
        }
    }
}

// ------------------------------ mega kernel --------------------------------
__global__ __launch_bounds__(256, 4) void mega(MegaArgs a)
{
    __shared__ __align__(16) char smem[36864];
    cg::grid_group grid = cg::this_grid();
    const int tid = threadIdx.x;
    const int NB  = gridDim.x;

    // ---------------- P0: prep (1600 units) ----------------
    for (int u = blockIdx.x; u < 1600; u += NB) {
        if (u < 512) {
            if (u == 0 && tid < 128) {   // ranges
                int b = tid & 63;
                const int* arr = (tid < 64) ? a.bh : a.bt;
                int base = (tid < 64) ? 0 : 128;
                int lo = 0, hi = NTOK;
                while (lo < hi) { int mid = (lo + hi) >> 1; if (arr[mid] < b) lo = mid + 1; else hi = mid; }
                int start = lo;
                lo = 0; hi = NTOK;
                while (lo < hi) { int mid = (lo + hi) >> 1; if (arr[mid] <= b) lo = mid + 1; else hi = mid; }
                a.ranges[base + b] = start;
                a.ranges[base + 64 + b] = lo;
            }
            // head conv: 8 rows x 40 chunks -> [4096][320]
            for (int idx = tid; idx < 8 * 40; idx += 256) {
                int r   = u * 8 + idx / 40;
                int col = (idx % 40) * 8;
                bf16x8 v;
                if (col + 8 <= 300) {
                    float4 f0 = *(const float4*)&a.h_head[(size_t)r * 300 + col];
                    float4 f1 = *(const float4*)&a.h_head[(size_t)r * 300 + col + 4];
                    v[0]=(__bf16)f0.x; v[1]=(__bf16)f0.y; v[2]=(__bf16)f0.z; v[3]=(__bf16)f0.w;
                    v[4]=(__bf16)f1.x; v[5]=(__bf16)f1.y; v[6]=(__bf16)f1.z; v[7]=(__bf16)f1.w;
                } else if (col < 300) {   // col == 296
                    float4 f0 = *(const float4*)&a.h_head[(size_t)r * 300 + col];
                    v[0]=(__bf16)f0.x; v[1]=(__bf16)f0.y; v[2]=(__bf16)f0.z; v[3]=(__bf16)f0.w;
                    v[4]=(__bf16)0.f; v[5]=(__bf16)0.f; v[6]=(__bf16)0.f; v[7]=(__bf16)0.f;
                } else {
                    #pragma unroll
                    for (int j = 0; j < 8; ++j) v[j] = (__bf16)0.f;
                }
                *(bf16x8*)&a.hh_bf[(size_t)r * KHEAD + col] = v;
            }
        } else if (u < 1024) {
            int q = u - 512;   // tail conv: 8 rows x 64 chunks
            for (int idx = tid; idx < 8 * 64; idx += 256) {
                int r   = q * 8 + (idx >> 6);
                int col = (idx & 63) * 8;
                float4 f0 = *(const float4*)&a.h_tail[(size_t)r * 512 + col];
                float4 f1 = *(const float4*)&a.h_tail[(size_t)r * 512 + col + 4];
                bf16x8 v;
                v[0]=(__bf16)f0.x; v[1]=(__bf16)f0.y; v[2]=(__bf16)f0.z; v[3]=(__bf16)f0.w;
                v[4]=(__bf16)f1.x; v[5]=(__bf16)f1.y; v[6]=(__bf16)f1.z; v[7]=(__bf16)f1.w;
                *(bf16x8*)&a.ht_bf[(size_t)r * 512 + col] = v;
            }
        } else {
            // transpose: w selects weight, t the 64x64 tile
            int t  = u - 1024;
            int w  = t >> 6;
            int j2 = t & 63;
            int tn = (j2 & 7) * 64;
            int tk = (j2 >> 3) * 64;
            const int K   = (w == 0) ? 300 : 512;
            const int ldT = (w == 0) ? KHEAD : 512;
            if (tk < ldT) {                       // block-uniform guard
                __bf16 (*T)[72] = (__bf16(*)[72])smem;
                __syncthreads();                  // prior unit's T reads done
                const float* src = a.tsrc[w];
                __bf16* dst = a.tdst[w];
                const int r0 = tid >> 4;
                const int c0 = (tid & 15) * 4;
                #pragma unroll
                for (int i = 0; i < 4; ++i) {
                    int k = tk + r0 + i * 16;
                    float4 v = (k < K) ? *(const float4*)&src[(size_t)k * 512 + tn + c0]
                                       : float4{0.f, 0.f, 0.f, 0.f};
                    T[r0 + i * 16][c0 + 0] = (__bf16)v.x;
                    T[r0 + i * 16][c0 + 1] = (__bf16)v.y;
                    T[r0 + i * 16][c0 + 2] = (__bf16)v.z;
                    T[r0 + i * 16][c0 + 3] = (__bf16)v.w;
                }
                __syncthreads();
                const int n  = tid >> 2;
                const int kk = (tid & 3) * 16;
                bf16x8 o0, o1;
                #pragma unroll
                for (int j = 0; j < 8; ++j) { o0[j] = T[kk + j][n]; o1[j] = T[kk + 8 + j][n]; }
                __bf16* dp = dst + (size_t)(tn + n) * ldT + tk + kk;
                *(bf16x8*)dp       = o0;
                *(bf16x8*)(dp + 8) = o1;
            }
        }
    }
    __threadfence();
    grid.sync();

    // ---------------- P1: map + qkv-tail (1024 units) ----------------
    for (int u = blockIdx.x; u < 1024; u += NB) {
        int z = u >> 8, t = u & 255;
        gemm_unit<__bf16>(a.g1A[z], a.g1W[z], a.g1b[z], a.g1C[z], a.g1K[z],
                          t & 3, t >> 2, smem);
    }
    __threadfence();
    grid.sync();

    // ---------------- P2: qkv-head (768 units) ----------------
    for (int u = blockIdx.x; u < 768; u += NB) {
        int z = u >> 8, t = u & 255;
        gemm_unit<__bf16>(a.g2A[z], a.g2W[z], a.g2b[z], a.g2C[z], 512,
                          t & 3, t >> 2, smem);
    }
    __threadfence();
    grid.sync();

    // ---------------- P3: attention (1024 units) ----------------
    for (int u = blockIdx.x; u < 1024; u += NB) {
        int side = u >> 9;
        int rem  = u & 511;
        attn_unit(a, side, rem & 7, rem >> 3, smem);
    }
    __threadfence();
    grid.sync();

    // ---------------- P4: out projections, fp32 (512 units) ----------------
    for (int u = blockIdx.x; u < 512; u += NB) {
        int z = u >> 8, t = u & 255;
        gemm_unit<float>(a.g4A[z], a.g4W[z], a.g4b[z], a.g4C[z], 512,
                         t & 3, t >> 2, smem);
    }
}

// ------------------------------ launcher -----------------------------------
extern "C" void kernel_launch(void* const* d_in, const int* in_sizes, int n_in,
                              void* d_out, int out_size, void* d_ws, size_t ws_size,
                              hipStream_t stream) {
    (void)in_sizes; (void)n_in; (void)out_size; (void)ws_size;

    const float* h_head = (const float*)d_in[0];
    const float* h_tail = (const float*)d_in[1];
    const int* batch_head = (const int*)d_in[2];
    const int* batch_tail = (const int*)d_in[3];
    const float* map_w = (const float*)d_in[4];
    const float* map_b = (const float*)d_in[5];
    const float* q1_w = (const float*)d_in[6];
    const float* q1_b = (const float*)d_in[7];
    const float* k1_w = (const float*)d_in[8];
    const float* k1_b = (const float*)d_in[9];
    const float* v1_w = (const float*)d_in[10];
    const float* v1_b = (const float*)d_in[11];
    const float* q2_w = (const float*)d_in[12];
    const float* q2_b = (const float*)d_in[13];
    const float* k2_w = (const float*)d_in[14];
    const float* k2_b = (const float*)d_in[15];
    const float* v2_w = (const float*)d_in[16];
    const float* v2_b = (const float*)d_in[17];
    const float* d1_w = (const float*)d_in[18];
    const float* d1_b = (const float*)d_in[19];
    const float* d2_w = (const float*)d_in[20];
    const float* d2_b = (const float*)d_in[21];

    float* out = (float*)d_out;

    const size_t SZ = (size_t)NTOK * HID;
    char* ws = (char*)d_ws;
    int* ranges = (int*)ws;                           // 1 KB
    __bf16* hh   = (__bf16*)(ws + 1024);
    __bf16* qh   = hh  + SZ;
    __bf16* kh   = qh  + SZ;
    __bf16* vh   = kh  + SZ;
    __bf16* qt   = vh  + SZ;
    __bf16* kt   = qt  + SZ;
    __bf16* vt   = kt  + SZ;
    __bf16* ctxh = vt  + SZ;
    __bf16* ctxt = ctxh + SZ;
    __bf16* mapT = ctxt + SZ;                         // [512][320]
    __bf16* q1T  = mapT + 512 * KHEAD;                // [512][512] each
    __bf16* k1T  = q1T + 512 * 512;
    __bf16* v1T  = k1T + 512 * 512;
    __bf16* q2T  = v1T + 512 * 512;
    __bf16* k2T  = q2T + 512 * 512;
    __bf16* v2T  = k2T + 512 * 512;
    __bf16* d1T  = v2T + 512 * 512;
    __bf16* d2T  = d1T + 512 * 512;
    __bf16* hh_bf = d2T + 512 * 512;                  // [4096][320]
    __bf16* ht_bf = hh_bf + (size_t)NTOK * KHEAD;     // [4096][512]

    MegaArgs ma;
    ma.h_head = h_head; ma.h_tail = h_tail; ma.bh = batch_head; ma.bt = batch_tail;
    ma.tsrc[0] = map_w; ma.tdst[0] = mapT;
    const float* wsrc[8] = {q1_w, k1_w, v1_w, q2_w, k2_w, v2_w, d1_w, d2_w};
    __bf16* wdst[8] = {q1T, k1T, v1T, q2T, k2T, v2T, d1T, d2T};
    for (int i = 0; i < 8; ++i) { ma.tsrc[i + 1] = wsrc[i]; ma.tdst[i + 1] = wdst[i]; }
    ma.hh_bf = hh_bf; ma.ht_bf = ht_bf; ma.ranges = ranges;

    ma.g1A[0] = hh_bf; ma.g1W[0] = mapT; ma.g1b[0] = map_b; ma.g1C[0] = hh; ma.g1K[0] = KHEAD;
    ma.g1A[1] = ht_bf; ma.g1W[1] = q2T;  ma.g1b[1] = q2_b;  ma.g1C[1] = qt; ma.g1K[1] = 512;
    ma.g1A[2] = ht_bf; ma.g1W[2] = k2T;  ma.g1b[2] = k2_b;  ma.g1C[2] = kt; ma.g1K[2] = 512;
    ma.g1A[3] = ht_bf; ma.g1W[3] = v2T;  ma.g1b[3] = v2_b;  ma.g1C[3] = vt; ma.g1K[3] = 512;

    ma.g2A[0] = hh; ma.g2W[0] = q1T; ma.g2b[0] = q1_b; ma.g2C[0] = qh;
    ma.g2A[1] = hh; ma.g2W[1] = k1T; ma.g2b[1] = k1_b; ma.g2C[1] = kh;
    ma.g2A[2] = hh; ma.g2W[2] = v1T; ma.g2b[2] = v1_b; ma.g2C[2] = vh;

    ma.qh = qh; ma.kh = kh; ma.vh = vh;
    ma.qt = qt; ma.kt = kt; ma.vt = vt;
    ma.ctxh = ctxh; ma.ctxt = ctxt;

    ma.g4A[0] = ctxh; ma.g4W[0] = d1T; ma.g4b[0] = d1_b; ma.g4C[0] = out;
    ma.g4A[1] = ctxt; ma.g4W[1] = d2T; ma.g4b[1] = d2_b; ma.g4C[1] = out + SZ;

    // grid = co-resident capacity (cooperative launch requirement), <= 1024
    int perCU = 0;
    hipError_t oe = hipOccupancyMaxActiveBlocksPerMultiprocessor(&perCU, mega, 256, 0);
    if (oe != hipSuccess || perCU <= 0) perCU = 2;
    if (perCU > 4) perCU = 4;
    int NB = perCU * 256;
    if (NB > 1024) NB = 1024;

    void* kp[] = { (void*)&ma };
    hipLaunchCooperativeKernel((const void*)mega, dim3(NB), dim3(256), kp, 0, stream);
}